// Round 10
// baseline (326.156 us; speedup 1.0000x reference)
//
#include <hip/hip_runtime.h>

// LSTM: B=4096, T=256, I=8, H=32, O=1, fp32 in/out, bf16 MFMA compute.
// R10 = R9 with the sync protocol FIXED. 256 blocks (1/CU) x 512 threads
// (8 waves, 2/SIMD). Block owns 16 batch rows; wave w owns hidden j = 4w + q
// (one (m,j) value per lane) via weight-row permutation
//   fr -> n = 32*(fr&3) + 4w + (fr>>2)   (weights are the MFMA FIRST operand)
// so lane (q,L) accum reg r = gate r at (m=L, j=4w+q); c/h update in-register.
//
// Sync: NO s_barrier, NO fences in the loop. Per-wave progress slots
// wstep[8]; wave w publishes wstep[w]=t+1 after its h(t+1) ds_write (ordered
// by per-wave in-order LDS + explicit s_waitcnt lgkmcnt(0) [0xC07F: vmcnt
// and expcnt left at max] + compiler-only asm barriers). Gate for body t:
// __all(wstep[lane&7] >= t) — a true MIN over waves (R9's aggregate counter
// let fast-wave surplus mask a laggard -> stale h reads). Min-gate bounds
// wave drift to <= 1 body, so the h double buffer is race-free.
// Nothing drains vmcnt in the loop -> the depth-4 register x-ring stays in
// flight across steps. Gate-g weight rows pre-scaled by 2*log2e (others
// log2e): 5 exp2 + 3 rcp per value.

#define T_LEN 256
#define LOG2E 1.4426950408889634f
#define WAIT_LGKM0 0xC07F   // s_waitcnt vmcnt(63) expcnt(7) lgkmcnt(0)

typedef short bf16x8 __attribute__((ext_vector_type(8)));
typedef float f32x4  __attribute__((ext_vector_type(4)));

static __device__ inline short f2bf_rne(float f) {          // one-time (weights)
    union { float f; unsigned u; } v; v.f = f;
    unsigned u = v.u;
    return (short)((u + 0x7FFFu + ((u >> 16) & 1u)) >> 16);
}
static __device__ inline short f2bf_fast(float f) {         // round-half-up
    union { float f; unsigned u; } v; v.f = f;
    return (short)((v.u + 0x8000u) >> 16);
}
static __device__ inline unsigned pack_bf2(float a, float b) {  // low=a, high=b
    union { float f; unsigned u; } x, y; x.f = a; y.f = b;
    return ((x.u + 0x8000u) >> 16) | ((y.u + 0x8000u) & 0xFFFF0000u);
}
static __device__ inline float bf2f(short s) {
    union { unsigned u; float f; } v;
    v.u = ((unsigned)(unsigned short)s) << 16;
    return v.f;
}

__global__ __launch_bounds__(512, 2) void lstm_kernel(
    const float* __restrict__ x, const float* __restrict__ W_ih,
    const float* __restrict__ W_hh, const float* __restrict__ b_ih,
    const float* __restrict__ b_hh, const float* __restrict__ W_out,
    const float* __restrict__ b_out, float* __restrict__ out)
{
    // h double buffer: [buf][m(0..15)][k(0..31)] bf16, row stride 40 shorts
    __shared__ __attribute__((aligned(16))) short h_lds[2][16 * 40];
    __shared__ unsigned wstep[8];      // per-wave published step

    const int tid  = threadIdx.x;
    const int w    = tid >> 6;         // wave 0..7 -> owns j = 4w + q
    const int lane = tid & 63;
    const int L    = lane & 15;        // batch row in tile / frag row
    const int q    = lane >> 4;        // quad
    const int row0 = blockIdx.x * 16;

    // ---- one-time: weight fragments (FIRST-operand layout [row=L][k=8q+j]) ----
    // row fr=L holds W row n = 32*(L&3) + 4w + (L>>2); gate = L&3,
    // scaled by log2e (gate-g rows: 2*log2e, folding tanh's factor 2).
    const int   n  = 32 * (L & 3) + 4 * w + (L >> 2);
    const float sc = ((L & 3) == 2 ? 2.f * LOG2E : LOG2E);
    bf16x8 whh_f, wih_f = (bf16x8){0,0,0,0,0,0,0,0};
    {
        const float* src = W_hh + n * 32 + q * 8;
#pragma unroll
        for (int j = 0; j < 8; ++j) whh_f[j] = f2bf_rne(src[j] * sc);
        if (q == 0) {                               // only k=0..7 exist (I=8)
            const float* s2 = W_ih + n * 8;
#pragma unroll
            for (int j = 0; j < 8; ++j) wih_f[j] = f2bf_rne(s2[j] * sc);
        }
    }
    // bias in C-layout: reg r -> row fr=4q+r -> n_r = 32r + 4w + q
    f32x4 bias;
#pragma unroll
    for (int r = 0; r < 4; ++r) {
        const int   nr = 32 * r + 4 * w + q;
        const float sr = (r == 2 ? 2.f * LOG2E : LOG2E);
        bias[r] = (b_ih[nr] + b_hh[nr]) * sr;
    }

    // zero h(0) buffer; init progress slots
    for (int i = tid; i < 16 * 40; i += 512) h_lds[0][i] = 0;
    if (tid < 8) wstep[tid] = 0;
    __syncthreads();                   // the only block barrier

    // ---- x prefetch ring, depth 4: slot s holds x(t), t === s (mod 4) ----
    // every lane loads its row's 32 B; quad duplicates served by L1.
    const float4* xv = (const float4*)x;
    const size_t  xb = (size_t)(row0 + L) * (T_LEN * 8 / 4);
    float4 r0[4], r1[4];
    const float4 a0 = xv[xb + 0], b0 = xv[xb + 1];   // x(0), consumed now
    r0[1] = xv[xb + 2]; r1[1] = xv[xb + 3];          // x(1)
    r0[2] = xv[xb + 4]; r1[2] = xv[xb + 5];          // x(2)
    r0[3] = xv[xb + 6]; r1[3] = xv[xb + 7];          // x(3)
    r0[0] = xv[xb + 8]; r1[0] = xv[xb + 9];          // x(4) -> slot 0

    // zx(0) from x(0)
    f32x4 zx;
    {
        unsigned uu[4];
        uu[0] = pack_bf2(a0.x, a0.y); uu[1] = pack_bf2(a0.z, a0.w);
        uu[2] = pack_bf2(b0.x, b0.y); uu[3] = pack_bf2(b0.z, b0.w);
        zx = __builtin_amdgcn_mfma_f32_16x16x32_bf16(wih_f, *(const bf16x8*)uu, bias, 0, 0, 0);
    }

    float c = 0.f;
    const int hr = L * 40 + q * 8;      // h-fragment read offset (shorts)
    const int hw = L * 40 + 4 * w + q;  // h write offset (this lane's j)
    volatile unsigned* wsp = &wstep[lane & 7];   // this lane's polled slot

#pragma unroll 2
    for (int t = 0; t < T_LEN; ++t) {
        // gate: MIN over waves >= t  <=>  every wave published h(t)
        // (and, being past body t-1, finished reading h(t-1) -> buffer safe)
        while (!__all(*wsp >= (unsigned)t)) {}
        asm volatile("" ::: "memory");   // compiler-only: no waitcnt emitted

        const int par = t & 1;
        const bf16x8 hfrag = *(const bf16x8*)(&h_lds[par][hr]);

        // recurrence MFMA (chain)
        const f32x4 acc = __builtin_amdgcn_mfma_f32_16x16x32_bf16(whh_f, hfrag, zx, 0, 0, 0);

        // off-chain: zx(t+1) from ring slot (t+1)&3; refill with x(t+5)
        {
            const int s = (t + 1) & 3;
            const float4 a = r0[s], b = r1[s];
            unsigned uu[4];
            uu[0] = pack_bf2(a.x, a.y); uu[1] = pack_bf2(a.z, a.w);
            uu[2] = pack_bf2(b.x, b.y); uu[3] = pack_bf2(b.z, b.w);
            zx = __builtin_amdgcn_mfma_f32_16x16x32_bf16(wih_f, *(const bf16x8*)uu, bias, 0, 0, 0);
            int tn = t + 5; if (tn >= T_LEN) tn = T_LEN - 1;
            r0[s] = xv[xb + (size_t)tn * 2];
            r1[s] = xv[xb + (size_t)tn * 2 + 1];
        }

        // activation: regs r = (i, f, g2, o); g rows pre-doubled.
        // sig(a)*tanh(b) = (1-eb)*rcp((1+ea)(1+eb)); only c-exp clamped.
        {
            const float ei = __builtin_amdgcn_exp2f(-acc[0]);
            const float ef = __builtin_amdgcn_exp2f(-acc[1]);
            const float eg = __builtin_amdgcn_exp2f(-acc[2]);
            const float eo = __builtin_amdgcn_exp2f(-acc[3]);
            const float fv = __builtin_amdgcn_rcpf(1.f + ef);
            const float ig = (1.f - eg) * __builtin_amdgcn_rcpf((1.f + ei) * (1.f + eg));
            c = fmaf(fv, c, ig);
            const float ec = __builtin_amdgcn_exp2f(fminf(c * (-2.f * LOG2E), 40.f));
            const float hv = (1.f - ec) * __builtin_amdgcn_rcpf((1.f + eo) * (1.f + ec));
            h_lds[par ^ 1][hw] = f2bf_fast(hv);
        }

        // publish: commit h-write (lgkm drain ONLY — vmcnt untouched, x-ring
        // stays in flight), then raise this wave's slot.
        asm volatile("" ::: "memory");
        __builtin_amdgcn_s_waitcnt(WAIT_LGKM0);
        if (lane == 0) *(volatile unsigned*)&wstep[w] = (unsigned)(t + 1);
        asm volatile("" ::: "memory");
    }

    // final gate: h(256) fully written (lives in buf[0] since 256 is even)
    while (!__all(*wsp >= (unsigned)T_LEN)) {}
    asm volatile("" ::: "memory");
    if (tid < 16) {
        float s = b_out[0];
#pragma unroll
        for (int k = 0; k < 32; ++k) s = fmaf(bf2f(h_lds[0][tid * 40 + k]), W_out[k], s);
        out[row0 + tid] = s;
    }
}

extern "C" void kernel_launch(void* const* d_in, const int* in_sizes, int n_in,
                              void* d_out, int out_size, void* d_ws, size_t ws_size,
                              hipStream_t stream) {
    const float* x     = (const float*)d_in[0];
    const float* W_ih  = (const float*)d_in[1];
    const float* W_hh  = (const float*)d_in[2];
    const float* b_ih  = (const float*)d_in[3];
    const float* b_hh  = (const float*)d_in[4];
    const float* W_out = (const float*)d_in[5];
    const float* b_out = (const float*)d_in[6];
    float* out = (float*)d_out;

    const int B = in_sizes[0] / (T_LEN * 8);  // 4096
    const int tiles = B / 16;                 // 256 blocks, one per CU
    lstm_kernel<<<tiles, 512, 0, stream>>>(x, W_ih, W_hh, b_ih, b_hh, W_out, b_out, out);
}

// Round 11
// 168.318 us; speedup vs baseline: 1.9377x; 1.9377x over previous
//
#include <hip/hip_runtime.h>

// LSTM: B=4096, T=256, I=8, H=32, O=1, fp32 in/out, bf16 MFMA compute.
// R11: TWO INDEPENDENT BARRIER DOMAINS PER CU. 512 blocks x 256 threads
// (4 waves); block owns 8 batch rows. Two co-resident blocks per CU have
// independent __syncthreads cadences -> their phases drift: block A's chain
// stalls (ds_read ~120, act chain, barrier skew) are filled by block B's
// issue on the same SIMDs. (R7's single 8-wave domain phase-locked all
// waves -> chain + issue ADDED; measured 713 cyc/step.)
// MFMA cost: B-operand cols 8..15 are garbage (8-row tile in a 16x16 MFMA,
// 2x redundant compute) — accepted: trans issue/SIMD 352 cyc < chain.
// Wave w computes j = 8w + 2q + e (e=0,1) via weight-row permutation
//   fr -> n = 32*(fr&3) + 8w + 2*(fr>>2) + e   (weights = FIRST operand)
// so lane (q,L) accum_e reg r = gate r at (m=L, j=8w+2q+e): adjacent j ->
// one packed b32 h-write; c/h update fully in-register.
// Step body: read hfrag -> 2 on-chain MFMAs -> act -> h-write -> [xfrag +
// 2 zx-MFMAs hidden in barrier wait] -> __syncthreads (drains lgkm only:
// loop is vm-free; x staged in LDS per 128-t chunk, one mid-loop restage).
// Gate-g rows pre-scaled by 2*log2e (others log2e): 5 exp2 + 3 rcp/value.

#define T_LEN   256
#define HALF_T  128
#define XSTRIDE 66    // shorts per timestep row (8 rows x 8 bf16 + 2 pad)
#define LOG2E   1.4426950408889634f

typedef short bf16x8 __attribute__((ext_vector_type(8)));
typedef float f32x4  __attribute__((ext_vector_type(4)));
typedef unsigned u32x4 __attribute__((ext_vector_type(4)));

static __device__ inline short f2bf_rne(float f) {          // one-time (weights)
    union { float f; unsigned u; } v; v.f = f;
    unsigned u = v.u;
    return (short)((u + 0x7FFFu + ((u >> 16) & 1u)) >> 16);
}
static __device__ inline unsigned pack_bf2(float a, float b) {  // low=a, high=b
    union { float f; unsigned u; } x, y; x.f = a; y.f = b;
    return ((x.u + 0x8000u) >> 16) | ((y.u + 0x8000u) & 0xFFFF0000u);
}
static __device__ inline float bf2f(short s) {
    union { unsigned u; float f; } v;
    v.u = ((unsigned)(unsigned short)s) << 16;
    return v.f;
}

__global__ __launch_bounds__(256, 2) void lstm_kernel(
    const float* __restrict__ x, const float* __restrict__ W_ih,
    const float* __restrict__ W_hh, const float* __restrict__ b_ih,
    const float* __restrict__ b_hh, const float* __restrict__ W_out,
    const float* __restrict__ b_out, float* __restrict__ out)
{
    // x chunk: [t_local(0..127)][row(0..7)][8] bf16
    __shared__ __attribute__((aligned(16))) short xl[HALF_T * XSTRIDE];   // 16.9 KB
    // h double buffer: [buf][m(0..15)][k(0..31)] bf16, row stride 40 shorts
    // (rows 8..15 hold garbage from MFMA cols 8..15 — harmless storage)
    __shared__ __attribute__((aligned(16))) short h_lds[2][16 * 40];      //  2.6 KB

    const int tid  = threadIdx.x;
    const int w    = tid >> 6;         // wave 0..3 -> j octet 8w..8w+7
    const int lane = tid & 63;
    const int L    = lane & 15;        // MFMA col = batch row (valid < 8)
    const int q    = lane >> 4;        // quad
    const int rbase = blockIdx.x * 8;  // block's first batch row
    const float4* xv = (const float4*)x;

    // ---- one-time: weight fragments (FIRST-operand layout [row=L][k=8q+j]) ----
    // MFMA e row fr=L holds W row n = 32*(L&3) + 8w + 2*(L>>2) + e,
    // scaled by log2e (gate-g rows: 2*log2e, folding tanh's factor 2).
    bf16x8 whh[2], wih[2];
    f32x4  bias[2];
#pragma unroll
    for (int e = 0; e < 2; ++e) {
        const int   n  = 32 * (L & 3) + 8 * w + 2 * (L >> 2) + e;
        const float sc = ((L & 3) == 2 ? 2.f * LOG2E : LOG2E);
        const float* src = W_hh + n * 32 + q * 8;
        bf16x8 fr;
#pragma unroll
        for (int j = 0; j < 8; ++j) fr[j] = f2bf_rne(src[j] * sc);
        whh[e] = fr;
        bf16x8 gr = (bf16x8){0,0,0,0,0,0,0,0};
        if (q == 0) {                              // only k=0..7 exist (I=8)
            const float* s2 = W_ih + n * 8;
#pragma unroll
            for (int j = 0; j < 8; ++j) gr[j] = f2bf_rne(s2[j] * sc);
        }
        wih[e] = gr;
        // bias in C-layout: reg r -> row fr=4q+r -> n_r = 32r + 8w + 2q + e
        f32x4 bb;
#pragma unroll
        for (int r = 0; r < 4; ++r) {
            const int   nr = 32 * r + 8 * w + 2 * q + e;
            const float sr = (r == 2 ? 2.f * LOG2E : LOG2E);
            bb[r] = (b_ih[nr] + b_hh[nr]) * sr;
        }
        bias[e] = bb;
    }

    // zero h(0) buffer
    for (int i = tid; i < 16 * 40; i += 256) h_lds[0][i] = 0;

    // ---- stage chunk 0 (t in [0,128)) : 128 t x 8 rows, 4 units/thread ----
#pragma unroll
    for (int it = 0; it < 4; ++it) {
        const int idx = tid + (it << 8);
        const int tl  = idx & (HALF_T - 1);
        const int L2  = idx >> 7;                  // 0..7
        const float4* srcp = xv + ((size_t)(rbase + L2) * T_LEN + tl) * 2;
        const float4 a = srcp[0], b = srcp[1];
        u32x4 u;
        u[0] = pack_bf2(a.x, a.y); u[1] = pack_bf2(a.z, a.w);
        u[2] = pack_bf2(b.x, b.y); u[3] = pack_bf2(b.z, b.w);
        *(u32x4*)(&xl[tl * XSTRIDE + L2 * 8]) = u;
    }
    __syncthreads();

    // zx(0) from x(0): B cols 8..15 read duplicate rows (broadcast, garbage ok)
    f32x4 zx[2];
    {
        const bf16x8 xf0 = *(const bf16x8*)(&xl[(L & 7) * 8]);
        zx[0] = __builtin_amdgcn_mfma_f32_16x16x32_bf16(wih[0], xf0, bias[0], 0, 0, 0);
        zx[1] = __builtin_amdgcn_mfma_f32_16x16x32_bf16(wih[1], xf0, bias[1], 0, 0, 0);
    }

    float c0 = 0.f, c1 = 0.f;
    const int hwo = L * 40 + 8 * w + 2 * q;        // h-write offset (shorts)

#pragma unroll 2
    for (int t = 0; t < T_LEN; ++t) {
        if (t == HALF_T - 1) {
            // chunk 0 fully consumed (last read was x(127) in body 126)
#pragma unroll
            for (int it = 0; it < 4; ++it) {
                const int idx = tid + (it << 8);
                const int tl  = idx & (HALF_T - 1);
                const int L2  = idx >> 7;
                const float4* srcp = xv + ((size_t)(rbase + L2) * T_LEN + HALF_T + tl) * 2;
                const float4 a = srcp[0], b = srcp[1];
                u32x4 u;
                u[0] = pack_bf2(a.x, a.y); u[1] = pack_bf2(a.z, a.w);
                u[2] = pack_bf2(b.x, b.y); u[3] = pack_bf2(b.z, b.w);
                *(u32x4*)(&xl[tl * XSTRIDE + L2 * 8]) = u;
            }
            __syncthreads();   // one-time vm drain; loop stays vm-free
        }

        const int par = t & 1, nxt = par ^ 1;

        // h(t) B-fragment [col=L][k=8q+j]
        const bf16x8 hfrag = *(const bf16x8*)(&h_lds[par][L * 40 + q * 8]);

        // on-chain MFMAs
        const f32x4 a0 = __builtin_amdgcn_mfma_f32_16x16x32_bf16(whh[0], hfrag, zx[0], 0, 0, 0);
        const f32x4 a1 = __builtin_amdgcn_mfma_f32_16x16x32_bf16(whh[1], hfrag, zx[1], 0, 0, 0);

        // activation: regs r = (i, f, g2, o); g rows pre-doubled.
        // sig(a)*tanh(b) = (1-eb)*rcp((1+ea)(1+eb)); only c-exp clamped.
        float h0, h1;
        {
            const float ei = __builtin_amdgcn_exp2f(-a0[0]);
            const float ef = __builtin_amdgcn_exp2f(-a0[1]);
            const float eg = __builtin_amdgcn_exp2f(-a0[2]);
            const float eo = __builtin_amdgcn_exp2f(-a0[3]);
            const float fv = __builtin_amdgcn_rcpf(1.f + ef);
            const float ig = (1.f - eg) * __builtin_amdgcn_rcpf((1.f + ei) * (1.f + eg));
            c0 = fmaf(fv, c0, ig);
            const float ec = __builtin_amdgcn_exp2f(fminf(c0 * (-2.f * LOG2E), 40.f));
            h0 = (1.f - ec) * __builtin_amdgcn_rcpf((1.f + eo) * (1.f + ec));
        }
        {
            const float ei = __builtin_amdgcn_exp2f(-a1[0]);
            const float ef = __builtin_amdgcn_exp2f(-a1[1]);
            const float eg = __builtin_amdgcn_exp2f(-a1[2]);
            const float eo = __builtin_amdgcn_exp2f(-a1[3]);
            const float fv = __builtin_amdgcn_rcpf(1.f + ef);
            const float ig = (1.f - eg) * __builtin_amdgcn_rcpf((1.f + ei) * (1.f + eg));
            c1 = fmaf(fv, c1, ig);
            const float ec = __builtin_amdgcn_exp2f(fminf(c1 * (-2.f * LOG2E), 40.f));
            h1 = (1.f - ec) * __builtin_amdgcn_rcpf((1.f + eo) * (1.f + ec));
        }

        // h(t+1) at (m=L, j=8w+2q / +1): adjacent -> single b32 store
        *(unsigned*)(&h_lds[nxt][hwo]) = pack_bf2(h0, h1);

        // off-chain: zx(t+1) — issued after the write, hides in barrier wait
        {
            int tn = t + 1; if (tn >= T_LEN) tn = T_LEN - 1;
            const bf16x8 xfrag = *(const bf16x8*)(&xl[(tn & (HALF_T - 1)) * XSTRIDE + (L & 7) * 8]);
            zx[0] = __builtin_amdgcn_mfma_f32_16x16x32_bf16(wih[0], xfrag, bias[0], 0, 0, 0);
            zx[1] = __builtin_amdgcn_mfma_f32_16x16x32_bf16(wih[1], xfrag, bias[1], 0, 0, 0);
        }

        __syncthreads();   // per-block barrier; other block on this CU drifts
    }

    // h(T) = h(256) lives in buf[0]; rows 0..7 are the real batch rows
    if (tid < 8) {
        float s = b_out[0];
#pragma unroll
        for (int k = 0; k < 32; ++k) s = fmaf(bf2f(h_lds[0][tid * 40 + k]), W_out[k], s);
        out[rbase + tid] = s;
    }
}

extern "C" void kernel_launch(void* const* d_in, const int* in_sizes, int n_in,
                              void* d_out, int out_size, void* d_ws, size_t ws_size,
                              hipStream_t stream) {
    const float* x     = (const float*)d_in[0];
    const float* W_ih  = (const float*)d_in[1];
    const float* W_hh  = (const float*)d_in[2];
    const float* b_ih  = (const float*)d_in[3];
    const float* b_hh  = (const float*)d_in[4];
    const float* W_out = (const float*)d_in[5];
    const float* b_out = (const float*)d_in[6];
    float* out = (float*)d_out;

    const int B = in_sizes[0] / (T_LEN * 8);  // 4096
    const int blocks = B / 8;                 // 512 blocks -> 2 per CU
    lstm_kernel<<<blocks, 256, 0, stream>>>(x, W_ih, W_hh, b_ih, b_hh, W_out, b_out, out);
}